// Round 4
// baseline (281.713 us; speedup 1.0000x reference)
//
#include <hip/hip_runtime.h>

// ContourIntegrationLayer: depthwise 3x3 conv, center tap masked to 0,
// SAME padding, + residual. x: [B,H,W,C] fp32 NHWC, kernel: [3,3,C] fp32.
// B=32 H=56 W=56 C=256.
//
// R1: XCD-aware block swizzle (kept).
// R2: vertical rolling window P=14 (kept). Compiler remat'd taps -> L1-bound.
// R3: asm-pinned taps -> allocator spilled to scratch. Reverted.
// R4: taps in LDS + contribution pipeline (kept). Clean traffic
//     (FETCH 56MB, WRITE 100MB), VGPR=32, 81.7us. Counters: HBM 24%,
//     VALU 10%, L1 9B/cyc/CU, LDS 22% -> ALL low = latency-bound.
//     Cause: unroll-1 loop loads a row then immediately consumes it
//     (vmcnt(0) per iteration, ~300-900cy exposed, ~4 waves/SIMD cover).
// R5: 1-deep register double-buffer prefetch. Issue row y+1's 3 loads
//     into the free buffer, compute row y from the other; the wait for
//     row y's data lands one full iteration (~150cy x 4 waves) after
//     issue. Steady loop unrolled x2 so buffer roles are static.

#define BB 32
#define HH 56
#define WW 56
#define C4 64            // 256 channels / 4 per float4
#define NXCD 8
#define P 14             // output rows per thread (56 = 4*14)
#define NHC 4            // h-chunks
#define ROWSTR (WW * C4) // float4 stride between image rows = 3584

// issue the 3 loads of row at pointer p into regs (Lr,Cr,Rr)
#define LOADROW3(Lr, Cr, Rr, p)                         \
    {                                                   \
        Cr = (p)[0];                                    \
        Lr = wl ? (p)[-C4] : zero;                      \
        Rr = wr ? (p)[ C4] : zero;                      \
    }

// T(y) = k0*L + k1*C + k2*R   -> contribution to output row y+1
#define CALC_T3(d, Lr, Cr, Rr)                              \
    {                                                       \
        float4 K0 = kl[0*C4], K1 = kl[1*C4], K2 = kl[2*C4]; \
        (d).x = K0.x*(Lr).x + K1.x*(Cr).x + K2.x*(Rr).x;    \
        (d).y = K0.y*(Lr).y + K1.y*(Cr).y + K2.y*(Rr).y;    \
        (d).z = K0.z*(Lr).z + K1.z*(Cr).z + K2.z*(Rr).z;    \
        (d).w = K0.w*(Lr).w + K1.w*(Cr).w + K2.w*(Rr).w;    \
    }

// M(y) = C (residual) + k3*L + k5*R  -> contribution to output row y
#define ADD_M3(d, Lr, Cr, Rr)                               \
    {                                                       \
        float4 K3 = kl[3*C4], K5 = kl[5*C4];                \
        (d).x += (Cr).x + K3.x*(Lr).x + K5.x*(Rr).x;        \
        (d).y += (Cr).y + K3.y*(Lr).y + K5.y*(Rr).y;        \
        (d).z += (Cr).z + K3.z*(Lr).z + K5.z*(Rr).z;        \
        (d).w += (Cr).w + K3.w*(Lr).w + K5.w*(Rr).w;        \
    }

// B(y) = k6*L + k7*C + k8*R  -> contribution to output row y-1
#define ADD_B3(d, Lr, Cr, Rr)                               \
    {                                                       \
        float4 K6 = kl[6*C4], K7 = kl[7*C4], K8 = kl[8*C4]; \
        (d).x += K6.x*(Lr).x + K7.x*(Cr).x + K8.x*(Rr).x;   \
        (d).y += K6.y*(Lr).y + K7.y*(Cr).y + K8.y*(Rr).y;   \
        (d).z += K6.z*(Lr).z + K7.z*(Cr).z + K8.z*(Rr).z;   \
        (d).w += K6.w*(Lr).w + K7.w*(Cr).w + K8.w*(Rr).w;   \
    }

// full processing of an interior row y (regs hold row y):
// completes out(y-1), stores it, builds out(y) partial, starts T(y)
#define PROC_FULL(Lr, Cr, Rr)                               \
    {                                                       \
        ADD_B3(pA, Lr, Cr, Rr);                             \
        *op = pA; op += ROWSTR;                             \
        ADD_M3(pB, Lr, Cr, Rr);                             \
        pA = pB;                                            \
        CALC_T3(pB, Lr, Cr, Rr);                            \
    }

__global__ __launch_bounds__(256, 7) void contour_kernel(
    const float4* __restrict__ x,     // [B*H*W*C4]
    const float4* __restrict__ kern,  // [9*C4]
    float4* __restrict__ out)         // [B*H*W*C4]
{
    // Kernel taps staged to LDS once per block (9 taps x 64 c4 x 16 B).
    __shared__ float4 lds_k[9 * C4];
    for (int i = threadIdx.x; i < 9 * C4; i += 256)
        lds_k[i] = kern[i];

    // XCD swizzle: remap so each XCD owns a contiguous chunk (4 images).
    const int nblocks = gridDim.x;          // 1792, divisible by 8
    const int per_xcd = nblocks / NXCD;     // 224
    const int xcd     = blockIdx.x % NXCD;
    const int local   = blockIdx.x / NXCD;
    const int blk     = xcd * per_xcd + local;

    int idx = blk * blockDim.x + threadIdx.x;
    int c4 = idx & (C4 - 1);      // == lane id
    int s  = idx >> 6;            // strip: ((b*NHC + hc)*WW + w)
    int w  = s % WW;              // constant per wave
    int t  = s / WW;
    int hc = t & (NHC - 1);       // constant per block
    int b  = t >> 2;              // constant per block

    __syncthreads();

    const float4 zero = make_float4(0.f, 0.f, 0.f, 0.f);
    const float4* kl = lds_k + c4;          // tap t at kl[t*C4]

    const int h0 = hc * P;
    const float4* xr = x   + (size_t)(b * HH + h0) * ROWSTR + w * C4 + c4;
    float4*       op = out + (size_t)(b * HH + h0) * ROWSTR + w * C4 + c4;

    const bool wl = (w > 0);        // wave-uniform
    const bool wr = (w < WW - 1);   // wave-uniform

    float4 La, Ca, Ra;   // row buffer A
    float4 Lb, Cb, Rb;   // row buffer B
    float4 pA;           // pending partial for output y-1
    float4 pB;           // pending partial for output y

    // slot -1 (row h0-1) -> A ; slot 0 (row h0) -> B (loads overlap)
    if (h0 > 0) { LOADROW3(La, Ca, Ra, xr - ROWSTR); }
    LOADROW3(Lb, Cb, Rb, xr);
    if (h0 > 0) { CALC_T3(pB, La, Ca, Ra); } else { pB = zero; }

    const float4* nrow = xr + ROWSTR;       // next row to fetch

    // issue slot 1 (row h0+1) -> A ; process slot 0 (row h0, in B)
    LOADROW3(La, Ca, Ra, nrow); nrow += ROWSTR;
    ADD_M3(pB, Lb, Cb, Rb);     // pB = out(h0) partial (no ADD_B: not ours)
    pA = pB;
    CALC_T3(pB, Lb, Cb, Rb);

    // steady: rows h0+1 .. h0+12, 6 iterations x 2 rows, static A/B roles
    #pragma unroll 1
    for (int j = 0; j < 6; ++j) {
        // odd slot in A; issue next -> B
        LOADROW3(Lb, Cb, Rb, nrow); nrow += ROWSTR;
        PROC_FULL(La, Ca, Ra);
        // even slot in B; issue next -> A
        LOADROW3(La, Ca, Ra, nrow); nrow += ROWSTR;
        PROC_FULL(Lb, Cb, Rb);
    }

    // slot 13 (row h0+13, in A): last output row of the strip.
    // issue slot 14 (row h0+P, bottom halo) -> B if it exists.
    const bool hasbot = (h0 + P < HH);      // block-uniform
    if (hasbot) { LOADROW3(Lb, Cb, Rb, nrow); }
    ADD_B3(pA, La, Ca, Ra);     // completes out(h0+12)
    *op = pA; op += ROWSTR;
    ADD_M3(pB, La, Ca, Ra);     // pB = out(h0+13) partial
    pA = pB;                    // (T(h0+13) belongs to next strip: skip)

    // slot 14 (row h0+P, in B): only its B contribution
    if (hasbot) { ADD_B3(pA, Lb, Cb, Rb); }
    *op = pA;                   // out(h0+13)
}

extern "C" void kernel_launch(void* const* d_in, const int* in_sizes, int n_in,
                              void* d_out, int out_size, void* d_ws, size_t ws_size,
                              hipStream_t stream) {
    const float4* x    = (const float4*)d_in[0];
    const float4* kern = (const float4*)d_in[1];
    float4* out        = (float4*)d_out;

    const int total = BB * NHC * WW * C4;           // 458,752 threads
    const int block = 256;
    const int grid  = (total + block - 1) / block;  // 1792 blocks (8*224)
    contour_kernel<<<grid, block, 0, stream>>>(x, kern, out);
}

// Round 6
// 190.283 us; speedup vs baseline: 1.4805x; 1.4805x over previous
//
#include <hip/hip_runtime.h>

// ContourIntegrationLayer: depthwise 3x3 conv, center tap masked to 0,
// SAME padding, + residual. x: [B,H,W,C] fp32 NHWC, kernel: [3,3,C] fp32.
// B=32 H=56 W=56 C=256.
//
// R1: XCD swizzle (kept). R2: P=14 rolling window (kept).
// R3: asm-pinned taps -> scratch spill. R5: reg double-buffer -> scratch
//     spill again (VGPR=36, +77MB both ways). Lesson: this allocator spills
//     any float4 kept live across other loads in the loop.
// R4: taps-in-LDS, load-then-consume: clean (VGPR=32, FETCH 56MB, WRITE
//     100MB) but latency-bound at 81.7us: per-row vmcnt(0) exposes ~900cy
//     HBM latency, ~7 waves/SIMD can't cover it.
// R6: async DMA pipeline. Rows go global->LDS via global_load_lds (NO
//     destination registers -> nothing to spill). Per-wave private 2-buffer
//     LDS row window; no __syncthreads in the loop (so no forced vmcnt(0)
//     drain); hand-counted vmcnt waits give a 2-iteration-deep pipeline.
//     Consume = ds_read_b128 just before use (R4's proven register shape).
//     lgkmcnt(0) before each stage-issue closes the ds_read-vs-DMA race.
// R6b: fix compile error — __builtin_nontemporal_store needs a clang
//      ext_vector_type pointer, not HIP_vector_type float4.

#define BB 32
#define HH 56
#define WW 56
#define C4 64            // 256 channels / 4 per float4
#define NXCD 8
#define P 14             // output rows per thread (56 = 4*14)
#define NHC 4            // h-chunks
#define ROWSTR (WW * C4) // float4 stride between image rows = 3584

typedef float f32x4 __attribute__((ext_vector_type(4)));

__device__ __forceinline__ void ntstore4(const float4& v, float4* p) {
    __builtin_nontemporal_store(*(const f32x4*)&v, (f32x4*)p);
}

__device__ __forceinline__ void async16(const float4* g, float4* l) {
    // 16B per lane, global (per-lane addr) -> LDS (wave-uniform base + lane*16)
    __builtin_amdgcn_global_load_lds(
        (const __attribute__((address_space(1))) void*)g,
        (__attribute__((address_space(3))) void*)l,
        16, 0, 0);
}

#define WAITV3 asm volatile("s_waitcnt vmcnt(3)" ::: "memory")
#define WAITV4 asm volatile("s_waitcnt vmcnt(4)" ::: "memory")
#define WAITV0 asm volatile("s_waitcnt vmcnt(0)" ::: "memory")
#define LGKM0  asm volatile("s_waitcnt lgkmcnt(0)" ::: "memory")

// T(y) = k0*L + k1*C + k2*R   -> contribution to output row y+1
#define CALC_T3(d)                                          \
    {                                                       \
        float4 K0 = kl[0*C4], K1 = kl[1*C4], K2 = kl[2*C4]; \
        (d).x = K0.x*Lv.x + K1.x*Cv.x + K2.x*Rv.x;          \
        (d).y = K0.y*Lv.y + K1.y*Cv.y + K2.y*Rv.y;          \
        (d).z = K0.z*Lv.z + K1.z*Cv.z + K2.z*Rv.z;          \
        (d).w = K0.w*Lv.w + K1.w*Cv.w + K2.w*Rv.w;          \
    }

// M(y) = C (residual) + k3*L + k5*R  -> contribution to output row y
#define ADD_M3(d)                                           \
    {                                                       \
        float4 K3 = kl[3*C4], K5 = kl[5*C4];                \
        (d).x += Cv.x + K3.x*Lv.x + K5.x*Rv.x;              \
        (d).y += Cv.y + K3.y*Lv.y + K5.y*Rv.y;              \
        (d).z += Cv.z + K3.z*Lv.z + K5.z*Rv.z;              \
        (d).w += Cv.w + K3.w*Lv.w + K5.w*Rv.w;              \
    }

// B(y) = k6*L + k7*C + k8*R  -> contribution to output row y-1
#define ADD_B3(d)                                           \
    {                                                       \
        float4 K6 = kl[6*C4], K7 = kl[7*C4], K8 = kl[8*C4]; \
        (d).x += K6.x*Lv.x + K7.x*Cv.x + K8.x*Rv.x;         \
        (d).y += K6.y*Lv.y + K7.y*Cv.y + K8.y*Rv.y;         \
        (d).z += K6.z*Lv.z + K7.z*Cv.z + K8.z*Rv.z;         \
        (d).w += K6.w*Lv.w + K7.w*Cv.w + K8.w*Rv.w;         \
    }

// read current row from LDS buffer (canonical lane*16 layout, conflict-free)
#define READROW(bslot)                                      \
    {                                                       \
        const float4* lb = lrb + (bslot) * 192;             \
        float4 Lt = lb[lane];                               \
        float4 Ct = lb[64 + lane];                          \
        float4 Rt = lb[128 + lane];                         \
        Lv = wl ? Lt : zero;                                \
        Cv = Ct;                                            \
        Rv = wr ? Rt : zero;                                \
    }

// issue async stage of image row 'srow' (clamped) into buffer bslot
#define STAGE(srow, bslot)                                  \
    {                                                       \
        int yc = (srow);                                    \
        yc = yc < 0 ? 0 : (yc > HH - 1 ? HH - 1 : yc);      \
        const float4* rb = xim + (size_t)yc * ROWSTR;       \
        float4* lb = lrb + (bslot) * 192;                   \
        async16(rb + oL, lb);                               \
        async16(rb + oC, lb + 64);                          \
        async16(rb + oR, lb + 128);                         \
    }

// steady step: consume row (in bslot), store out(row-1), stage row+2
#define STEP_MID(bslot, srow)                               \
    {                                                       \
        WAITV4;                                             \
        READROW(bslot);                                     \
        ADD_B3(pA);                                         \
        ntstore4(pA, op); op += ROWSTR;                     \
        ADD_M3(pB);                                         \
        pA = pB;                                            \
        CALC_T3(pB);                                        \
        LGKM0;                                              \
        STAGE(srow, bslot);                                 \
    }

__global__ __launch_bounds__(256, 4) void contour_kernel(
    const float4* __restrict__ x,     // [B*H*W*C4]
    const float4* __restrict__ kern,  // [9*C4]
    float4* __restrict__ out)         // [B*H*W*C4]
{
    // taps staged once (before any DMA, so the barrier can't drain stages)
    __shared__ float4 lds_k[9 * C4];            //  9216 B
    __shared__ float4 lds_rows[4][2][3][C4];    // 24576 B (per-wave private)
    for (int i = threadIdx.x; i < 9 * C4; i += 256)
        lds_k[i] = kern[i];
    __syncthreads();

    // XCD swizzle: each XCD owns a contiguous chunk (4 whole images).
    const int nblocks = gridDim.x;          // 1792, divisible by 8
    const int per_xcd = nblocks / NXCD;     // 224
    const int blk = (blockIdx.x % NXCD) * per_xcd + blockIdx.x / NXCD;

    const int lane = threadIdx.x & 63;      // == c4
    const int wv   = threadIdx.x >> 6;
    int s  = (blk * 256 + threadIdx.x) >> 6;  // strip: ((b*NHC+hc)*WW + w)
    int w  = s % WW;                          // constant per wave
    int t  = s / WW;
    int hc = t & (NHC - 1);                   // constant per block
    int b  = t >> 2;                          // constant per block

    const float4 zero = make_float4(0.f, 0.f, 0.f, 0.f);
    const float4* kl  = lds_k + lane;         // tap t at kl[t*C4]
    float4*       lrb = &lds_rows[wv][0][0][0];

    const bool wl = (w > 0);
    const bool wr = (w < WW - 1);
    // clamped column offsets (float4 units, include lane)
    const int oC = w * C4 + lane;
    const int oL = (wl ? w - 1 : 0) * C4 + lane;
    const int oR = (wr ? w + 1 : WW - 1) * C4 + lane;

    const int h0 = hc * P;
    const float4* xim = x + (size_t)(b * HH) * ROWSTR;
    float4* op = out + (size_t)(b * HH + h0) * ROWSTR + w * C4 + lane;

    float4 Lv, Cv, Rv;   // current row (short-lived)
    float4 pA, pB;       // pending partials

    // prologue: stage rows h0-1 (clamped) and h0
    STAGE(h0 - 1, 0);
    STAGE(h0,     1);

    // s=0: row h0-1 (top halo) -> T only
    WAITV3;
    if (h0 > 0) { READROW(0); CALC_T3(pB); }
    else        { pB = zero; }
    LGKM0;
    STAGE(h0 + 1, 0);

    // s=1: row h0 -> M (out(h0-1) not ours)
    WAITV3;
    READROW(1);
    ADD_M3(pB);
    pA = pB;
    CALC_T3(pB);
    LGKM0;
    STAGE(h0 + 2, 1);

    // s=2: row h0+1 -> first store (out(h0))
    WAITV3;
    READROW(0);
    ADD_B3(pA);
    ntstore4(pA, op); op += ROWSTR;
    ADD_M3(pB);
    pA = pB;
    CALC_T3(pB);
    LGKM0;
    STAGE(h0 + 3, 0);

    // s=3..12: steady (rows h0+2 .. h0+11), static buffer roles
    int srow = h0 + 4;
    #pragma unroll 1
    for (int j = 0; j < 5; ++j) {
        STEP_MID(1, srow); srow++;
        STEP_MID(0, srow); srow++;
    }

    // s=13: row h0+12, stages row h0+14 (stage(15))
    STEP_MID(1, srow);

    // s=14: row h0+13, no further stage
    WAITV4;
    READROW(0);
    ADD_B3(pA);
    ntstore4(pA, op); op += ROWSTR;
    ADD_M3(pB);
    pA = pB;   // out(h0+13) partial; T(h0+13) belongs to next strip

    // s=15: row h0+14 (bottom halo) -> B only
    WAITV0;
    const bool hasbot = (h0 + P < HH);      // block-uniform
    if (hasbot) {
        READROW(1);
        ADD_B3(pA);
    }
    ntstore4(pA, op);    // out(h0+13)
}

extern "C" void kernel_launch(void* const* d_in, const int* in_sizes, int n_in,
                              void* d_out, int out_size, void* d_ws, size_t ws_size,
                              hipStream_t stream) {
    const float4* x    = (const float4*)d_in[0];
    const float4* kern = (const float4*)d_in[1];
    float4* out        = (float4*)d_out;

    const int total = BB * NHC * WW * C4;           // 458,752 threads
    const int block = 256;
    const int grid  = (total + block - 1) / block;  // 1792 blocks (8*224)
    contour_kernel<<<grid, block, 0, stream>>>(x, kern, out);
}

// Round 7
// 186.094 us; speedup vs baseline: 1.5138x; 1.0225x over previous
//
#include <hip/hip_runtime.h>

// ContourIntegrationLayer: depthwise 3x3 conv, center tap masked to 0,
// SAME padding, + residual. x: [B,H,W,C] fp32 NHWC, kernel: [3,3,C] fp32.
// B=32 H=56 W=56 C=256.
//
// R1: XCD swizzle (kept). R2: P=14 strip (kept).
// R3/R5: reg-resident taps / reg double-buffer -> allocator spills. Dead end.
// R4: taps-in-LDS load-consume: clean but latency-bound (81.7us).
// R6: per-wave async DMA pipeline (global_load_lds, depth 2 rows): 67.5us,
//     clean traffic (FETCH 55MB WRITE 100MB, VGPR=56). Cycles/wave-step only
//     437->362: the 2-step window (~720cy) < DMA latency (~900-1300cy when
//     missing L3, 56% of reads) -> every step still exposes 200-600cy.
// R7: 2 rows per pipeline step (8 steps x 2 rows). Same LDS (2 slots x 2
//     rows x 3 cols/wave + taps = 33.8KB, 4 blocks/CU), but wait-to-use
//     distance doubles to ~1400cy > worst DMA latency. Waits halve, tap
//     reads CSE across the row pair, stages issue before the FMA block.
//     Steady vmcnt(8) = prev step's 6 stages + 2 stores; needed data is
//     always older -> extra compiler vmem ops only tighten, never break.

#define BB 32
#define HH 56
#define WW 56
#define C4 64            // 256 channels / 4 per float4
#define NXCD 8
#define P 14             // output rows per thread (56 = 4*14)
#define NHC 4            // h-chunks
#define ROWSTR (WW * C4) // float4 stride between image rows = 3584

typedef float f32x4 __attribute__((ext_vector_type(4)));

__device__ __forceinline__ void ntstore4(const float4& v, float4* p) {
    __builtin_nontemporal_store(*(const f32x4*)&v, (f32x4*)p);
}

__device__ __forceinline__ void async16(const float4* g, float4* l) {
    // 16B/lane, global (per-lane addr) -> LDS (wave-uniform base + lane*16)
    __builtin_amdgcn_global_load_lds(
        (const __attribute__((address_space(1))) void*)g,
        (__attribute__((address_space(3))) void*)l,
        16, 0, 0);
}

#define WAITV2 asm volatile("s_waitcnt vmcnt(2)" ::: "memory")
#define WAITV6 asm volatile("s_waitcnt vmcnt(6)" ::: "memory")
#define WAITV8 asm volatile("s_waitcnt vmcnt(8)" ::: "memory")
#define LGKM0  asm volatile("s_waitcnt lgkmcnt(0)" ::: "memory")

// contribution macros, parameterized on the row registers
// CT: d = k0*L + k1*C + k2*R          (T(y) -> feeds out(y+1))
#define CT(d, L, C, R)                                      \
    {                                                       \
        float4 K0 = kl[0*C4], K1 = kl[1*C4], K2 = kl[2*C4]; \
        (d).x = K0.x*(L).x + K1.x*(C).x + K2.x*(R).x;       \
        (d).y = K0.y*(L).y + K1.y*(C).y + K2.y*(R).y;       \
        (d).z = K0.z*(L).z + K1.z*(C).z + K2.z*(R).z;       \
        (d).w = K0.w*(L).w + K1.w*(C).w + K2.w*(R).w;       \
    }
// AM: d += C + k3*L + k5*R            (M(y)+residual -> out(y))
#define AM(d, L, C, R)                                      \
    {                                                       \
        float4 K3 = kl[3*C4], K5 = kl[5*C4];                \
        (d).x += (C).x + K3.x*(L).x + K5.x*(R).x;           \
        (d).y += (C).y + K3.y*(L).y + K5.y*(R).y;           \
        (d).z += (C).z + K3.z*(L).z + K5.z*(R).z;           \
        (d).w += (C).w + K3.w*(L).w + K5.w*(R).w;           \
    }
// AB: d += k6*L + k7*C + k8*R         (B(y) -> completes out(y-1))
#define AB(d, L, C, R)                                      \
    {                                                       \
        float4 K6 = kl[6*C4], K7 = kl[7*C4], K8 = kl[8*C4]; \
        (d).x += K6.x*(L).x + K7.x*(C).x + K8.x*(R).x;      \
        (d).y += K6.y*(L).y + K7.y*(C).y + K8.y*(R).y;      \
        (d).z += K6.z*(L).z + K7.z*(C).z + K8.z*(R).z;      \
        (d).w += K6.w*(L).w + K7.w*(C).w + K8.w*(R).w;      \
    }

// read both rows of a slot into (L0,C0,R0),(L1,C1,R1); SAME-pad via selects
#define READ2(slot)                                         \
    {                                                       \
        const float4* q = lrb + (slot) * 384;               \
        float4 a = q[lane],       bq = q[ 64+lane], cq = q[128+lane]; \
        float4 d = q[192+lane],   e  = q[256+lane], f  = q[320+lane]; \
        L0 = wl ? a : zero;  C0 = bq;  R0 = wr ? cq : zero; \
        L1 = wl ? d : zero;  C1 = e;   R1 = wr ? f  : zero; \
    }

// stage image rows ra, rb (clamped) into a slot's two row sub-buffers
#define STAGE2(ra, rb, slot)                                \
    {                                                       \
        int ya = (ra); ya = ya < 0 ? 0 : (ya > HH-1 ? HH-1 : ya); \
        int yb = (rb); yb = yb < 0 ? 0 : (yb > HH-1 ? HH-1 : yb); \
        const float4* pa = xim + (size_t)ya * ROWSTR;       \
        const float4* pb = xim + (size_t)yb * ROWSTR;       \
        float4* la = lrb + (slot) * 384;                    \
        async16(pa + oL, la);       async16(pa + oC, la +  64); \
        async16(pa + oR, la + 128); async16(pb + oL, la + 192); \
        async16(pb + oC, la + 256); async16(pb + oR, la + 320); \
    }

// full interior row: completes out(y-1), stores, advances partials
#define ROWFULL(L, C, R)                                    \
    {                                                       \
        AB(pA, L, C, R);                                    \
        ntstore4(pA, op); op += ROWSTR;                     \
        AM(pB, L, C, R);                                    \
        pA = pB;                                            \
        CT(pB, L, C, R);                                    \
    }

// steady step: consume slot (2 rows), stage next 2 rows into same slot
#define STEP2(slot, sra)                                    \
    {                                                       \
        WAITV8;                                             \
        READ2(slot);                                        \
        LGKM0;                                              \
        STAGE2((sra), (sra) + 1, slot);                     \
        ROWFULL(L0, C0, R0);                                \
        ROWFULL(L1, C1, R1);                                \
    }

__global__ __launch_bounds__(256, 4) void contour_kernel(
    const float4* __restrict__ x,     // [B*H*W*C4]
    const float4* __restrict__ kern,  // [9*C4]
    float4* __restrict__ out)         // [B*H*W*C4]
{
    // taps staged once (before any DMA so the barrier can't drain stages)
    __shared__ float4 lds_k[9 * C4];              //  9216 B
    __shared__ float4 lds_rows[4][2][2][3][C4];   // 24576 B (per-wave private)
    for (int i = threadIdx.x; i < 9 * C4; i += 256)
        lds_k[i] = kern[i];
    __syncthreads();

    // XCD swizzle: each XCD owns a contiguous chunk (4 whole images).
    const int nblocks = gridDim.x;          // 1792, divisible by 8
    const int per_xcd = nblocks / NXCD;     // 224
    const int blk = (blockIdx.x % NXCD) * per_xcd + blockIdx.x / NXCD;

    const int lane = threadIdx.x & 63;      // == c4
    const int wv   = threadIdx.x >> 6;
    int s  = (blk * 256 + threadIdx.x) >> 6;  // strip: ((b*NHC+hc)*WW + w)
    int w  = s % WW;                          // constant per wave
    int t  = s / WW;
    int hc = t & (NHC - 1);                   // constant per block
    int b  = t >> 2;                          // constant per block

    const float4 zero = make_float4(0.f, 0.f, 0.f, 0.f);
    const float4* kl  = lds_k + lane;         // tap i at kl[i*C4]
    float4*       lrb = &lds_rows[wv][0][0][0][0];  // slot stride 384

    const bool wl = (w > 0);
    const bool wr = (w < WW - 1);
    // clamped column offsets (float4 units, include lane)
    const int oC = w * C4 + lane;
    const int oL = (wl ? w - 1 : 0) * C4 + lane;
    const int oR = (wr ? w + 1 : WW - 1) * C4 + lane;

    const int h0 = hc * P;
    const float4* xim = x + (size_t)(b * HH) * ROWSTR;
    float4* op = out + (size_t)(b * HH + h0) * ROWSTR + w * C4 + lane;

    float4 L0, C0, R0, L1, C1, R1;   // current row pair (short-lived)
    float4 pA, pB;                   // pending partials

    // prologue: slot0 <- rows (h0-1, h0); slot1 <- rows (h0+1, h0+2)
    STAGE2(h0 - 1, h0,     0);
    STAGE2(h0 + 1, h0 + 2, 1);

    // step A: consume slot0 = rows h0-1 (halo: T only), h0 (M,T)
    WAITV6;                          // retire slot0's 6; slot1's 6 in flight
    READ2(0);
    LGKM0;
    STAGE2(h0 + 3, h0 + 4, 0);
    if (h0 > 0) { CT(pB, L0, C0, R0); } else { pB = zero; }
    AM(pB, L1, C1, R1);              // pB = out(h0) partial
    pA = pB;
    CT(pB, L1, C1, R1);              // pB = T(h0)

    // step B: consume slot1 = rows h0+1, h0+2 -> stores out(h0), out(h0+1)
    WAITV6;                          // newest 6 = A's stages; slot1 retired
    READ2(1);
    LGKM0;
    STAGE2(h0 + 5, h0 + 6, 1);
    ROWFULL(L0, C0, R0);
    ROWFULL(L1, C1, R1);

    // steps C..F: rows h0+3..h0+10, stages up to rows h0+13, h0+14
    int srow = h0 + 7;
    #pragma unroll 1
    for (int j = 0; j < 2; ++j) {
        STEP2(0, srow); srow += 2;   // C: slot0  E: slot0
        STEP2(1, srow); srow += 2;   // D: slot1  F: slot1
    }

    // step G: consume slot0 = rows h0+11, h0+12 (no stage)
    WAITV8;                          // newest 8 = F's 6 stages + 2 stores
    READ2(0);
    ROWFULL(L0, C0, R0);
    ROWFULL(L1, C1, R1);

    // step H: consume slot1 = rows h0+13, h0+14(halo)
    WAITV2;                          // newest 2 = G's stores; F's stages done
    READ2(1);
    AB(pA, L0, C0, R0);              // completes out(h0+12)
    ntstore4(pA, op); op += ROWSTR;
    AM(pB, L0, C0, R0);              // pB = out(h0+13) partial
    pA = pB;
    const bool hasbot = (h0 + P < HH);   // block-uniform
    if (hasbot) { AB(pA, L1, C1, R1); } // B(h0+14)
    ntstore4(pA, op);                // out(h0+13)
}

extern "C" void kernel_launch(void* const* d_in, const int* in_sizes, int n_in,
                              void* d_out, int out_size, void* d_ws, size_t ws_size,
                              hipStream_t stream) {
    const float4* x    = (const float4*)d_in[0];
    const float4* kern = (const float4*)d_in[1];
    float4* out        = (float4*)d_out;

    const int total = BB * NHC * WW * C4;           // 458,752 threads
    const int block = 256;
    const int grid  = (total + block - 1) / block;  // 1792 blocks (8*224)
    contour_kernel<<<grid, block, 0, stream>>>(x, kern, out);
}